// Round 8
// baseline (223.585 us; speedup 1.0000x reference)
//
#include <hip/hip_runtime.h>
#include <hip/hip_bf16.h>

#define T_  30
#define B_  64
#define V_  32
#define F_  128
#define L_  64
#define LF_ 64
#define TH_ 20
#define H_  4
#define HD_ 32

typedef __attribute__((ext_vector_type(8))) short bf16x8;   // 8 bf16 = 4 VGPR
typedef __attribute__((ext_vector_type(4))) float f32x4;
#define MFMA(a,b,c) __builtin_amdgcn_mfma_f32_16x16x32_bf16(a, b, c, 0, 0, 0)

__device__ __forceinline__ float bf1(unsigned short u) {
    unsigned int x = ((unsigned int)u) << 16; float f; __builtin_memcpy(&f, &x, 4); return f;
}
__device__ __forceinline__ unsigned short f2bf(float f) {
    unsigned int x; __builtin_memcpy(&x, &f, 4);
    x += 0x7fffu + ((x >> 16) & 1u);          // RTNE
    return (unsigned short)(x >> 16);
}
// packed f32x2 -> bf16x2 (low = a, high = b); hardware packed cvt where available
__device__ __forceinline__ unsigned int pkbf(float a, float b) {
    __hip_bfloat162 h = __float22bfloat162_rn(make_float2(a, b));
    unsigned int u; __builtin_memcpy(&u, &h, 4); return u;
}
// 8-contiguous-element fragment from global (A- or B-operand), either dtype
__device__ __forceinline__ bf16x8 ldfrag(const void* p, size_t elem, bool isBf16) {
    if (isBf16) return *(const bf16x8*)((const unsigned short*)p + elem);
    const float* f = (const float*)p + elem;
    float4 a = *(const float4*)f;
    float4 b = *(const float4*)(f + 4);
    uint4 u = { pkbf(a.x, a.y), pkbf(a.z, a.w), pkbf(b.x, b.y), pkbf(b.z, b.w) };
    bf16x8 r; __builtin_memcpy(&r, &u, 16); return r;
}

// One block per (b,v). 4 waves; wave w = head w = f/g-slice [32w,32w+32).
// All LDS wave-private except sO; 2 barriers total. XOR-swizzled 16B chunks
// (chunk ^= row) -> conflict-free ds_read_b128 with zero padding.
// LDS map (ushort units, total 20480 = 40960 B -> 4 blocks/CU):
//   per wave w: kb=w*3072   sK [64][32]   (overlaid by sP [32][64] after scores)
//               qb=kb+2048  sQ [32][32]
//               vb=12288+w*2048  sVt [32][64]  (V^T, d-slice rows)
//   shared:     ob=12288    sO [32][128]  (overlays the 4 sVt slices; 2 barriers)
__global__ __launch_bounds__(256, 4)
void lane_attn_kernel(const void* __restrict__ veh,    // [T,B,V,F]
                      const void* __restrict__ lanes,  // [B,V,L,LF]
                      const void* __restrict__ maskp,  // [TH,B,V,L] uint8 or int32 (probed)
                      const void* __restrict__ Wk, const void* __restrict__ Wv,
                      const void* __restrict__ Wq, const void* __restrict__ Wc,
                      float* __restrict__ outp)        // [T,B,V,F] fp32
{
    const int bv   = blockIdx.x;
    const int tid  = threadIdx.x;
    const int w    = tid >> 6;
    const int lane = tid & 63;
    const int quad = lane >> 4;
    const int lm   = lane & 15;
    const int fbase = w * 32;

    __shared__ __align__(16) unsigned short S[20480];
    const int kb = w * 3072, qb = kb + 2048, vb = 12288 + w * 2048;
    const int pb = kb, ob = 12288;

    // ---------- per-wave probes ----------
    const unsigned short* vh16 = (const unsigned short*)veh;
    const int fld = (vh16[2 * lane] >> 7) & 0xFF;
    const bool isBf16 = __popcll(__ballot(fld >= 100 && fld <= 130)) >= 32;
    const unsigned char* mbp = (const unsigned char*)maskp;
    const bool maskByte = (__ballot(mbp[4 * lane + 1] != 0) != 0ULL);

    // ---------- mask OR over TH (lane = l) -> 64-bit bitmask ----------
    unsigned long long okmask;
    {
        const int* mi = (const int*)maskp;
        int o = 0;
        #pragma unroll
        for (int th = 0; th < TH_; ++th) {
            const size_t e = (size_t)th * (B_ * V_ * L_) + (size_t)bv * L_ + lane;
            o |= maskByte ? (int)mbp[e] : mi[e];
        }
        okmask = __ballot(o != 0);
    }

    // ---------- Phase B-K: K = lanes @ Wk^T -> sK (wave f-slice) ----------
    {
        bf16x8 wb[2][2];
        #pragma unroll
        for (int kt = 0; kt < 2; ++kt)
            #pragma unroll
            for (int nt = 0; nt < 2; ++nt)
                wb[kt][nt] = ldfrag(Wk, (size_t)(fbase + nt * 16 + lm) * LF_ + kt * 32 + quad * 8, isBf16);
        f32x4 acc[2][4];
        #pragma unroll
        for (int nt = 0; nt < 2; ++nt)
            #pragma unroll
            for (int mt = 0; mt < 4; ++mt) acc[nt][mt] = (f32x4)0.f;
        #pragma unroll
        for (int kt = 0; kt < 2; ++kt) {
            bf16x8 a[4];
            #pragma unroll
            for (int mt = 0; mt < 4; ++mt)
                a[mt] = ldfrag(lanes, (size_t)(bv * L_ + mt * 16 + lm) * LF_ + kt * 32 + quad * 8, isBf16);
            #pragma unroll
            for (int nt = 0; nt < 2; ++nt)
                #pragma unroll
                for (int mt = 0; mt < 4; ++mt) acc[nt][mt] = MFMA(a[mt], wb[kt][nt], acc[nt][mt]);
        }
        #pragma unroll
        for (int nt = 0; nt < 2; ++nt) {
            const int chunkc = nt * 2 + (lm >> 3);
            #pragma unroll
            for (int mt = 0; mt < 4; ++mt)
                #pragma unroll
                for (int r = 0; r < 4; ++r) {
                    const int l = mt * 16 + quad * 4 + r;
                    S[kb + l * 32 + ((chunkc ^ (l & 3)) << 3) + (lm & 7)] = f2bf(acc[nt][mt][r]);
                }
        }
    }
    // ---------- Phase B-V: V -> sVt (V^T, wave d-slice), r-pair packed stores ----------
    {
        bf16x8 wb[2][2];
        #pragma unroll
        for (int kt = 0; kt < 2; ++kt)
            #pragma unroll
            for (int nt = 0; nt < 2; ++nt)
                wb[kt][nt] = ldfrag(Wv, (size_t)(fbase + nt * 16 + lm) * LF_ + kt * 32 + quad * 8, isBf16);
        f32x4 acc[2][4];
        #pragma unroll
        for (int nt = 0; nt < 2; ++nt)
            #pragma unroll
            for (int mt = 0; mt < 4; ++mt) acc[nt][mt] = (f32x4)0.f;
        #pragma unroll
        for (int kt = 0; kt < 2; ++kt) {
            bf16x8 a[4];
            #pragma unroll
            for (int mt = 0; mt < 4; ++mt)
                a[mt] = ldfrag(lanes, (size_t)(bv * L_ + mt * 16 + lm) * LF_ + kt * 32 + quad * 8, isBf16);
            #pragma unroll
            for (int nt = 0; nt < 2; ++nt)
                #pragma unroll
                for (int mt = 0; mt < 4; ++mt) acc[nt][mt] = MFMA(a[mt], wb[kt][nt], acc[nt][mt]);
        }
        #pragma unroll
        for (int nt = 0; nt < 2; ++nt) {
            const int dd = nt * 16 + lm;
            #pragma unroll
            for (int mt = 0; mt < 4; ++mt)
                #pragma unroll
                for (int jp = 0; jp < 2; ++jp) {
                    const int l0 = mt * 16 + quad * 4 + jp * 2;
                    *(unsigned int*)&S[vb + dd * 64 + (((l0 >> 3) ^ (dd & 7)) << 3) + (l0 & 7)]
                        = pkbf(acc[nt][mt][jp * 2], acc[nt][mt][jp * 2 + 1]);
                }
        }
    }

    // ---------- Phase C: Q = veh @ Wq^T -> sQ (wave g-slice), pre-scaled ----------
    {
        bf16x8 wq[4][2];
        #pragma unroll
        for (int kt = 0; kt < 4; ++kt)
            #pragma unroll
            for (int nt = 0; nt < 2; ++nt)
                wq[kt][nt] = ldfrag(Wq, (size_t)(fbase + nt * 16 + lm) * F_ + kt * 32 + quad * 8, isBf16);
        f32x4 acc[2][2];
        #pragma unroll
        for (int nt = 0; nt < 2; ++nt)
            #pragma unroll
            for (int mt = 0; mt < 2; ++mt) acc[nt][mt] = (f32x4)0.f;
        #pragma unroll
        for (int kt = 0; kt < 4; ++kt) {
            bf16x8 a[2];
            #pragma unroll
            for (int mt = 0; mt < 2; ++mt) {
                const int t = mt * 16 + lm;
                const int tc = (t < T_) ? t : (T_ - 1);   // clamp; values flushed later
                a[mt] = ldfrag(veh, (size_t)(tc * (B_ * V_) + bv) * F_ + kt * 32 + quad * 8, isBf16);
            }
            #pragma unroll
            for (int nt = 0; nt < 2; ++nt)
                #pragma unroll
                for (int mt = 0; mt < 2; ++mt) acc[nt][mt] = MFMA(a[mt], wq[kt][nt], acc[nt][mt]);
        }
        const float scl = 0.17677669529663687f;   // 1/sqrt(32)
        #pragma unroll
        for (int nt = 0; nt < 2; ++nt) {
            const int chunkc = nt * 2 + (lm >> 3);
            #pragma unroll
            for (int mt = 0; mt < 2; ++mt)
                #pragma unroll
                for (int r = 0; r < 4; ++r) {   // t&3 == r
                    const int t = mt * 16 + quad * 4 + r;
                    S[qb + t * 32 + ((chunkc ^ r) << 3) + (lm & 7)] = f2bf(acc[nt][mt][r] * scl);
                }
        }
    }

    // ---------- Scores: S^T[l][t] = K . Q (wave = head; all LDS wave-private) ----------
    f32x4 sacc[4][2];
    {
        bf16x8 a[4], b[2];
        #pragma unroll
        for (int mt = 0; mt < 4; ++mt) {
            const int l = mt * 16 + lm;
            a[mt] = *(const bf16x8*)&S[kb + l * 32 + ((quad ^ (l & 3)) << 3)];
        }
        #pragma unroll
        for (int nt = 0; nt < 2; ++nt) {
            const int t = nt * 16 + lm;
            b[nt] = *(const bf16x8*)&S[qb + t * 32 + ((quad ^ (t & 3)) << 3)];
        }
        #pragma unroll
        for (int mt = 0; mt < 4; ++mt)
            #pragma unroll
            for (int nt = 0; nt < 2; ++nt) sacc[mt][nt] = MFMA(a[mt], b[nt], (f32x4)0.f);
    }

    // ---------- exp + mask in regs -> transposed packed store to sP (overlays sK) ----------
    {
        #pragma unroll
        for (int nt = 0; nt < 2; ++nt) {
            const int t = nt * 16 + lm;
            const bool tok = (t < T_);
            #pragma unroll
            for (int mt = 0; mt < 4; ++mt)
                #pragma unroll
                for (int jp = 0; jp < 2; ++jp) {
                    const int l0 = mt * 16 + quad * 4 + jp * 2;
                    const float p0 = (tok && ((okmask >> l0) & 1))       ? __expf(sacc[mt][nt][jp * 2])     : 0.f;
                    const float p1 = (tok && ((okmask >> (l0 + 1)) & 1)) ? __expf(sacc[mt][nt][jp * 2 + 1]) : 0.f;
                    const int chunk = 2 * mt + (quad >> 1);
                    *(unsigned int*)&S[pb + t * 64 + ((chunk ^ (t & 7)) << 3) + ((quad & 1) * 4 + jp * 2)]
                        = pkbf(p0, p1);
                }
        }
    }

    // ---------- PV + ones-MFMA row sums (wave-private) ----------
    f32x4 pacc[2][2], ssum[2];
    {
        bf16x8 bones;
        #pragma unroll
        for (int j = 0; j < 8; ++j) bones[j] = (short)0x3F80;
        #pragma unroll
        for (int mt = 0; mt < 2; ++mt) {
            ssum[mt] = (f32x4)0.f;
            #pragma unroll
            for (int nt = 0; nt < 2; ++nt) pacc[mt][nt] = (f32x4)0.f;
        }
        #pragma unroll
        for (int kt = 0; kt < 2; ++kt) {
            bf16x8 a[2], b[2];
            #pragma unroll
            for (int mt = 0; mt < 2; ++mt) {
                const int t = mt * 16 + lm;
                a[mt] = *(const bf16x8*)&S[pb + t * 64 + (((kt * 4 + quad) ^ (t & 7)) << 3)];
            }
            #pragma unroll
            for (int nt = 0; nt < 2; ++nt) {
                const int dd = nt * 16 + lm;
                b[nt] = *(const bf16x8*)&S[vb + dd * 64 + (((kt * 4 + quad) ^ (dd & 7)) << 3)];
            }
            #pragma unroll
            for (int mt = 0; mt < 2; ++mt) {
                ssum[mt] = MFMA(a[mt], bones, ssum[mt]);
                #pragma unroll
                for (int nt = 0; nt < 2; ++nt) pacc[mt][nt] = MFMA(a[mt], b[nt], pacc[mt][nt]);
            }
        }
    }
    // preload E weight fragments (latency hidden across barriers)
    bf16x8 wc[4][2];
    #pragma unroll
    for (int kt = 0; kt < 4; ++kt)
        #pragma unroll
        for (int nt = 0; nt < 2; ++nt)
            wc[kt][nt] = ldfrag(Wc, (size_t)(fbase + nt * 16 + lm) * F_ + kt * 32 + quad * 8, isBf16);

    __syncthreads();   // barrier A: all waves' sVt reads done before sO overwrites

    // ---------- normalize + store sO (shared, overlays sVt block) ----------
    {
        #pragma unroll
        for (int mt = 0; mt < 2; ++mt)
            #pragma unroll
            for (int r = 0; r < 4; ++r) {
                const float s = ssum[mt][r];
                const float inv = (s > 0.f) ? 1.f / s : 0.f;   // pad rows -> exact 0
                const int t = mt * 16 + quad * 4 + r;
                #pragma unroll
                for (int nt = 0; nt < 2; ++nt) {
                    const int f = fbase + nt * 16 + lm;
                    S[ob + t * 128 + (((f >> 3) ^ (t & 15)) << 3) + (lm & 7)] = f2bf(pacc[mt][nt][r] * inv);
                }
            }
    }
    __syncthreads();   // barrier B: sO complete

    // ---------- Phase E: out = O @ Wc^T + veh ----------
    {
        f32x4 acc[2][2];
        #pragma unroll
        for (int nt = 0; nt < 2; ++nt)
            #pragma unroll
            for (int mt = 0; mt < 2; ++mt) acc[nt][mt] = (f32x4)0.f;
        #pragma unroll
        for (int kt = 0; kt < 4; ++kt) {
            bf16x8 a[2];
            #pragma unroll
            for (int mt = 0; mt < 2; ++mt) {
                const int t = mt * 16 + lm;
                a[mt] = *(const bf16x8*)&S[ob + t * 128 + (((kt * 4 + quad) ^ (t & 15)) << 3)];
            }
            #pragma unroll
            for (int nt = 0; nt < 2; ++nt)
                #pragma unroll
                for (int mt = 0; mt < 2; ++mt) acc[nt][mt] = MFMA(a[mt], wc[kt][nt], acc[nt][mt]);
        }
        #pragma unroll
        for (int nt = 0; nt < 2; ++nt) {
            const int g = fbase + nt * 16 + lm;
            #pragma unroll
            for (int mt = 0; mt < 2; ++mt)
                #pragma unroll
                for (int r = 0; r < 4; ++r) {
                    const int t = mt * 16 + quad * 4 + r;
                    if (t < T_) {
                        const size_t off = ((size_t)t * (B_ * V_) + bv) * F_ + g;
                        const float res = isBf16 ? bf1(((const unsigned short*)veh)[off])
                                                 : ((const float*)veh)[off];
                        outp[off] = acc[nt][mt][r] + res;
                    }
                }
        }
    }
}

extern "C" void kernel_launch(void* const* d_in, const int* in_sizes, int n_in,
                              void* d_out, int out_size, void* d_ws, size_t ws_size,
                              hipStream_t stream) {
    (void)in_sizes; (void)n_in; (void)out_size; (void)d_ws; (void)ws_size;
    lane_attn_kernel<<<dim3(B_ * V_), dim3(256), 0, stream>>>(
        d_in[0], d_in[1], d_in[2], d_in[3], d_in[4], d_in[5], d_in[6],
        (float*)d_out);
}